// Round 9
// baseline (188.243 us; speedup 1.0000x reference)
//
#include <hip/hip_runtime.h>
#include <math.h>

#define DF 8192
#define NT 1024

// float4-slot swizzle: slot bits 0-2 ^= bits 3-5. Verified per-pattern: every
// structured sweep spreads 8 lanes across all 8 bank-quads (uniform).
#define SW4(i) ((i) ^ (((i) >> 3) & 7))

// wave-private sync: all my LDS ops complete; no reordering across
#define WAVE_SYNC asm volatile("s_waitcnt lgkmcnt(0)" ::: "memory")

typedef float cf2 __attribute__((ext_vector_type(2)));
typedef float cf4 __attribute__((ext_vector_type(4)));

#define RT_C 0.92387953251128674f
#define RT_S 0.38268343236508977f
#define RT_H 0.70710678118654752f

// scalar complex (twiddle chains, shared across both rows)
struct sc { float re, im; };
__device__ __forceinline__ sc smul(sc a, sc b) { return sc{a.re * b.re - a.im * b.im, a.re * b.im + a.im * b.re}; }
__device__ __forceinline__ sc smi(sc a) { return sc{a.im, -a.re}; }   // a * -i
__device__ __forceinline__ sc spi(sc a) { return sc{-a.im, a.re}; }   // a * +i

// dual-row packed butterflies: data = (re pair, im pair), scalar twiddle
__device__ __forceinline__ void pdif(cf2& ar, cf2& ai, cf2& br, cf2& bi, sc W) {
    cf2 dr = ar - br, di = ai - bi;
    ar += br; ai += bi;
    br = dr * W.re - di * W.im;
    bi = dr * W.im + di * W.re;
}
__device__ __forceinline__ void pdit(cf2& ar, cf2& ai, cf2& br, cf2& bi, sc W) {
    cf2 wr = br * W.re - bi * W.im;
    cf2 wi = br * W.im + bi * W.re;
    br = ar - wr; bi = ai - wi;
    ar += wr; ai += wi;
}
__device__ __forceinline__ void pdit1(cf2& ar, cf2& ai, cf2& br, cf2& bi) {
    cf2 tr = br, ti = bi;
    br = ar - tr; bi = ai - ti;
    ar += tr; ai += ti;
}
__device__ __forceinline__ void pditi(cf2& ar, cf2& ai, cf2& br, cf2& bi) {
    cf2 wr = -bi, wi = br;
    br = ar - wr; bi = ai - wi;
    ar += wr; ai += wi;
}

// 3 radix-2 DIF stages on 8 elems (R5-verified twiddle scheme); w = exp(-i*pi*lo/(4s))
__device__ __forceinline__ void fft8_dif_p(cf2 vr[8], cf2 vi[8], sc w) {
    sc w2 = smul(w, w), w4 = smul(w2, w2);
    pdif(vr[0], vi[0], vr[4], vi[4], w);
    pdif(vr[1], vi[1], vr[5], vi[5], smul(w, sc{RT_H, -RT_H}));
    pdif(vr[2], vi[2], vr[6], vi[6], smi(w));
    pdif(vr[3], vi[3], vr[7], vi[7], smul(w, sc{-RT_H, -RT_H}));
    pdif(vr[0], vi[0], vr[2], vi[2], w2);
    pdif(vr[1], vi[1], vr[3], vi[3], smi(w2));
    pdif(vr[4], vi[4], vr[6], vi[6], w2);
    pdif(vr[5], vi[5], vr[7], vi[7], smi(w2));
    pdif(vr[0], vi[0], vr[1], vi[1], w4);
    pdif(vr[2], vi[2], vr[3], vi[3], w4);
    pdif(vr[4], vi[4], vr[5], vi[5], w4);
    pdif(vr[6], vi[6], vr[7], vi[7], w4);
}

// 2 radix-2 DIT stages on 4 elems (R5-verified); q = exp(+i*pi*lo/(2s))
__device__ __forceinline__ void fft4_dit_p(cf2 ur[4], cf2 ui[4], sc q) {
    sc q2 = smul(q, q);
    pdit(ur[0], ui[0], ur[1], ui[1], q2);
    pdit(ur[2], ui[2], ur[3], ui[3], q2);
    pdit(ur[0], ui[0], ur[2], ui[2], q);
    pdit(ur[1], ui[1], ur[3], ui[3], spi(q));
}

__device__ __forceinline__ int brev10(int x) { return (int)(__brev((unsigned)x) >> 22); }

__device__ __forceinline__ cf2 shfl_xor_cf2(cf2 v, int mask) {
    double d;
    __builtin_memcpy(&d, &v, 8);
    d = __shfl_xor(d, mask);
    cf2 r;
    __builtin_memcpy(&r, &d, 8);
    return r;
}

// Dual-row SoA: slot = float4 (reA, reB, imA, imB). R5's verified index/twiddle
// math at NT=1024: F1(4096,2048,1024) F2(512,256,128) F3(64,32,16) F4(8,4,2)
// MEGA(1 + Hermitian + inv 1,2) S2(4,8) S3(16,32) S4(64,128) S5(256,512) S6(1024,2048).
__global__ __launch_bounds__(NT, 4)
void mcb9(const float* __restrict__ x, const float* __restrict__ y,
          const float* __restrict__ s1, const float* __restrict__ s2,
          const float* __restrict__ gamma, const float* __restrict__ beta,
          const int* __restrict__ h1, const int* __restrict__ h2,
          float* __restrict__ out)
{
    __shared__ cf4 z4[DF];   // 128 KB: both rows
    float* zf = (float*)z4;
    const int t    = threadIdx.x;
    const int lane = t & 63;
    const int wv   = t >> 6;
    const int rA = blockIdx.x * 2, rB = rA + 1;

    // ---- zero ----
    #pragma unroll
    for (int m = 0; m < 8; ++m) z4[t + NT * m] = cf4{0.f, 0.f, 0.f, 0.f};
    __syncthreads();

    // ---- count sketches: x*s1 -> re(A,B), y*s2 -> im(A,B) ----
    {
        float2 xa = ((const float2*)(x + (size_t)rA * 2048))[t];
        float2 xb = ((const float2*)(x + (size_t)rB * 2048))[t];
        float2 sv = ((const float2*)s1)[t];
        int2   hv = ((const int2*)h1)[t];
        int p0 = SW4(hv.x), p1 = SW4(hv.y);
        atomicAdd(zf + 4 * p0 + 0, xa.x * sv.x);
        atomicAdd(zf + 4 * p0 + 1, xb.x * sv.x);
        atomicAdd(zf + 4 * p1 + 0, xa.y * sv.y);
        atomicAdd(zf + 4 * p1 + 1, xb.y * sv.y);
        float ya = (y + (size_t)rA * 1024)[t];
        float yb = (y + (size_t)rB * 1024)[t];
        float tv = s2[t];
        int q0 = SW4(h2[t]);
        atomicAdd(zf + 4 * q0 + 2, ya * tv);
        atomicAdd(zf + 4 * q0 + 3, yb * tv);
    }
    __syncthreads();

    float sn, cs;
    cf2 vr[8], vi[8];

    // ---------- F1: h=4096,2048,1024 ; slot = t + 1024m ----------
    #pragma unroll
    for (int m = 0; m < 8; ++m) { cf4 q = z4[SW4(t + 1024 * m)]; vr[m] = q.lo; vi[m] = q.hi; }
    __sincosf(-(float)M_PI / 4096.f * (float)t, &sn, &cs);
    fft8_dif_p(vr, vi, sc{cs, sn});
    #pragma unroll
    for (int m = 0; m < 8; ++m) { cf4 q; q.lo = vr[m]; q.hi = vi[m]; z4[SW4(t + 1024 * m)] = q; }
    __syncthreads();

    // ---------- F2: h=512,256,128 ; slot = lo + 128m + 1024hi (2-wave regions) ----------
    {
        const int lo = t & 127, hi = t >> 7;
        #pragma unroll
        for (int m = 0; m < 8; ++m) { cf4 q = z4[SW4(lo + 128 * m + 1024 * hi)]; vr[m] = q.lo; vi[m] = q.hi; }
        __sincosf(-(float)M_PI / 512.f * (float)lo, &sn, &cs);
        fft8_dif_p(vr, vi, sc{cs, sn});
        #pragma unroll
        for (int m = 0; m < 8; ++m) { cf4 q; q.lo = vr[m]; q.hi = vi[m]; z4[SW4(lo + 128 * m + 1024 * hi)] = q; }
    }
    __syncthreads();

    // ---------- F3: h=64,32,16 ; slot = lo + 16m + 128hi (16-thread regions, wave-private) ----------
    {
        const int lo = t & 15, hi = t >> 4;
        #pragma unroll
        for (int m = 0; m < 8; ++m) { cf4 q = z4[SW4(lo + 16 * m + 128 * hi)]; vr[m] = q.lo; vi[m] = q.hi; }
        __sincosf(-(float)M_PI / 64.f * (float)lo, &sn, &cs);
        fft8_dif_p(vr, vi, sc{cs, sn});
        #pragma unroll
        for (int m = 0; m < 8; ++m) { cf4 q; q.lo = vr[m]; q.hi = vi[m]; z4[SW4(lo + 16 * m + 128 * hi)] = q; }
    }
    WAVE_SYNC;

    // ---------- F4: h=8,4,2 ; slot = lo + 2m + 16hi, lo=t&1 (2-thread regions, wave-private) ----------
    {
        const int lo = t & 1, hi = t >> 1;
        #pragma unroll
        for (int m = 0; m < 8; ++m) { cf4 q = z4[SW4(lo + 2 * m + 16 * hi)]; vr[m] = q.lo; vi[m] = q.hi; }
        sc w = lo ? sc{RT_C, -RT_S} : sc{1.f, 0.f};   // exp(-i*pi*lo/8)
        fft8_dif_p(vr, vi, w);
        #pragma unroll
        for (int m = 0; m < 8; ++m) { cf4 q; q.lo = vr[m]; q.hi = vi[m]; z4[SW4(lo + 2 * m + 16 * hi)] = q; }
    }
    __syncthreads();   // MEGA partner reads are cross-wave

    // ---------- MEGA: h=1 + Hermitian product + U-prep + inverse h=1,2 (R5-verified pairing) ----
    // Pre-h1 pairs (2j,2j+1), j=4t+g. Post-h1: even=Z[kappa], odd=Z[kappa+4096],
    // kappa = 1024*brev2(g) + R, R=brev10(t). Partner: thread tp=brev10(1024-R), pair 3-g;
    // t==0: own pairs TBL={0,1,3,2}, swap at g==0.
    cf2 ur[4], ui[4];
    {
        const int R  = brev10(t);
        const int tp = (R == 0) ? 0 : brev10(1024 - R);
        __sincosf((float)M_PI / 4096.f * (float)R, &sn, &cs);
        const sc wR = sc{cs, sn};
        const float q4 = 0.25f / 8192.f;
        const sc rc[4] = { sc{1.f, 0.f}, sc{0.f, 1.f}, sc{RT_H, RT_H}, sc{-RT_H, RT_H} };
        const int TBL[4] = {0, 1, 3, 2};
        #pragma unroll
        for (int g = 0; g < 4; ++g) {
            cf4 e0 = z4[SW4(8 * t + 2 * g)];
            cf4 e1 = z4[SW4(8 * t + 2 * g + 1)];
            cf2 Ar = e0.lo + e1.lo, Ai = e0.hi + e1.hi;    // h=1 butterfly
            cf2 Br = e0.lo - e1.lo, Bi = e0.hi - e1.hi;
            int pb = (t == 0) ? (2 * TBL[g]) : (8 * tp + 2 * (3 - g));
            cf4 r0 = z4[SW4(pb)];
            cf4 r1 = z4[SW4(pb + 1)];
            cf2 PAr = r0.lo + r1.lo, PAi = r0.hi + r1.hi;
            cf2 PBr = r0.lo - r1.lo, PBi = r0.hi - r1.hi;
            if (t == 0 && g == 0) {   // kappa=0 self-pair: swap
                cf2 s0 = PAr; PAr = PBr; PBr = s0;
                cf2 s1_ = PAi; PAi = PBi; PBi = s1_;
            }
            // P1 = (A + conj PB)*(-i)(A - conj PB)*q4 ; P2 analog with B,PA
            cf2 T1r = Ar + PBr, T1i = Ai - PBi;
            cf2 T2r = Ai + PBi, T2i = PBr - Ar;
            cf2 P1r = (T1r * T2r - T1i * T2i) * q4;
            cf2 P1i = (T1r * T2i + T1i * T2r) * q4;
            cf2 U1r = Br + PAr, U1i = Bi - PAi;
            cf2 U2r = Bi + PAi, U2i = PAr - Br;
            cf2 P2r = (U1r * U2r - U1i * U2i) * q4;
            cf2 P2i = (U1r * U2i + U1i * U2r) * q4;
            sc W = smul(wR, rc[g]);
            cf2 Sr = P1r + P2r, Si = P1i + P2i;
            cf2 Dr = P1r - P2r, Di = P1i - P2i;
            cf2 Dwr = Dr * W.re - Di * W.im;
            cf2 Dwi = Dr * W.im + Di * W.re;
            ur[g] = Sr - Dwi;
            ui[g] = Si + Dwr;
        }
        // inverse h=1: W=1 ; h=2: W={1,i}
        pdit1(ur[0], ui[0], ur[1], ui[1]);
        pdit1(ur[2], ui[2], ur[3], ui[3]);
        pdit1(ur[0], ui[0], ur[2], ui[2]);
        pditi(ur[1], ui[1], ur[3], ui[3]);
    }
    __syncthreads();   // all pair/partner reads complete before overwrite
    #pragma unroll
    for (int c = 0; c < 4; ++c) { cf4 q; q.lo = ur[c]; q.hi = ui[c]; z4[SW4(4 * t + c)] = q; }
    WAVE_SYNC;         // S2 readers are in the writer's own wave

    // ---------- S2: h=4,8 ; slot = lo + 4m + 16hi (wave-private) ----------
    {
        const int lo = t & 3, hi = t >> 2;
        #pragma unroll
        for (int m = 0; m < 4; ++m) { cf4 q = z4[SW4(lo + 4 * m + 16 * hi)]; ur[m] = q.lo; ui[m] = q.hi; }
        __sincosf((float)M_PI / 8.f * (float)lo, &sn, &cs);
        fft4_dit_p(ur, ui, sc{cs, sn});
        #pragma unroll
        for (int m = 0; m < 4; ++m) { cf4 q; q.lo = ur[m]; q.hi = ui[m]; z4[SW4(lo + 4 * m + 16 * hi)] = q; }
    }
    WAVE_SYNC;

    // ---------- S3: h=16,32 ; slot = lo + 16m + 64hi (wave-private) ----------
    {
        const int lo = t & 15, hi = t >> 4;
        #pragma unroll
        for (int m = 0; m < 4; ++m) { cf4 q = z4[SW4(lo + 16 * m + 64 * hi)]; ur[m] = q.lo; ui[m] = q.hi; }
        __sincosf((float)M_PI / 32.f * (float)lo, &sn, &cs);
        fft4_dit_p(ur, ui, sc{cs, sn});
        #pragma unroll
        for (int m = 0; m < 4; ++m) { cf4 q; q.lo = ur[m]; q.hi = ui[m]; z4[SW4(lo + 16 * m + 64 * hi)] = q; }
    }
    WAVE_SYNC;

    // ---------- S4: h=64,128 ; slot = lo + 64m + 256hi (wave-private) ----------
    {
        const int lo = t & 63, hi = t >> 6;
        #pragma unroll
        for (int m = 0; m < 4; ++m) { cf4 q = z4[SW4(lo + 64 * m + 256 * hi)]; ur[m] = q.lo; ui[m] = q.hi; }
        __sincosf((float)M_PI / 128.f * (float)lo, &sn, &cs);
        fft4_dit_p(ur, ui, sc{cs, sn});
        #pragma unroll
        for (int m = 0; m < 4; ++m) { cf4 q; q.lo = ur[m]; q.hi = ui[m]; z4[SW4(lo + 64 * m + 256 * hi)] = q; }
    }
    __syncthreads();   // S5 regions span 4 waves

    // ---------- S5: h=256,512 ; slot = lo + 256m + 1024hi ----------
    {
        const int lo = t & 255, hi = t >> 8;
        #pragma unroll
        for (int m = 0; m < 4; ++m) { cf4 q = z4[SW4(lo + 256 * m + 1024 * hi)]; ur[m] = q.lo; ui[m] = q.hi; }
        __sincosf((float)M_PI / 512.f * (float)lo, &sn, &cs);
        fft4_dit_p(ur, ui, sc{cs, sn});
        #pragma unroll
        for (int m = 0; m < 4; ++m) { cf4 q; q.lo = ur[m]; q.hi = ui[m]; z4[SW4(lo + 256 * m + 1024 * hi)] = q; }
    }
    __syncthreads();

    // ---------- S6: h=1024,2048 ; slot = t + 1024m ; LN + L2 from regs ----------
    #pragma unroll
    for (int m = 0; m < 4; ++m) { cf4 q = z4[SW4(t + 1024 * m)]; ur[m] = q.lo; ui[m] = q.hi; }
    __sincosf((float)M_PI / 2048.f * (float)t, &sn, &cs);
    fft4_dit_p(ur, ui, sc{cs, sn});
    // elem n = t+1024m: fused[2n] = ur (rows A,B), fused[2n+1] = ui

    cf2 ps = cf2{0.f, 0.f}, pq = cf2{0.f, 0.f};
    #pragma unroll
    for (int m = 0; m < 4; ++m) {
        ps += ur[m] + ui[m];
        pq += ur[m] * ur[m] + ui[m] * ui[m];
    }
    #pragma unroll
    for (int k = 32; k >= 1; k >>= 1) { ps += shfl_xor_cf2(ps, k); pq += shfl_xor_cf2(pq, k); }
    __syncthreads();                    // all S6 reads complete before stash
    if (lane == 0) { cf4 q; q.lo = ps; q.hi = pq; z4[wv] = q; }
    __syncthreads();
    cf2 ts = cf2{0.f, 0.f}, tq = cf2{0.f, 0.f};
    #pragma unroll
    for (int w = 0; w < 16; ++w) { cf4 s = z4[w]; ts += s.lo; tq += s.hi; }
    const cf2 mu2 = ts * (1.f / (float)DF);
    const cf2 var2 = tq * (1.f / (float)DF) - mu2 * mu2;
    const cf2 rstd2 = cf2{rsqrtf(var2.x + 1e-5f), rsqrtf(var2.y + 1e-5f)};

    const float2* g2  = (const float2*)gamma;
    const float2* bt2 = (const float2*)beta;
    cf2 pl = cf2{0.f, 0.f};
    #pragma unroll
    for (int m = 0; m < 4; ++m) {
        int i = t + 1024 * m;
        float2 g = g2[i], bb = bt2[i];
        cf2 nr = (ur[m] - mu2) * rstd2 * g.x + bb.x;
        cf2 ni = (ui[m] - mu2) * rstd2 * g.y + bb.y;
        ur[m] = nr; ui[m] = ni;
        pl += nr * nr + ni * ni;
    }
    #pragma unroll
    for (int k = 32; k >= 1; k >>= 1) pl += shfl_xor_cf2(pl, k);
    if (lane == 0) { cf4 q; q.lo = pl; q.hi = cf2{0.f, 0.f}; z4[16 + wv] = q; }
    __syncthreads();
    cf2 tl = cf2{0.f, 0.f};
    #pragma unroll
    for (int w = 0; w < 16; ++w) tl += z4[16 + w].lo;
    const float invA = 1.f / fmaxf(sqrtf(tl.x), 1e-12f);
    const float invB = 1.f / fmaxf(sqrtf(tl.y), 1e-12f);

    float2* oA = (float2*)(out + (size_t)rA * DF);
    float2* oB = (float2*)(out + (size_t)rB * DF);
    #pragma unroll
    for (int m = 0; m < 4; ++m) {
        int i = t + 1024 * m;
        oA[i] = make_float2(ur[m].x * invA, ui[m].x * invA);
        oB[i] = make_float2(ur[m].y * invB, ui[m].y * invB);
    }
}

extern "C" void kernel_launch(void* const* d_in, const int* in_sizes, int n_in,
                              void* d_out, int out_size, void* d_ws, size_t ws_size,
                              hipStream_t stream) {
    const float* x     = (const float*)d_in[0];
    const float* y     = (const float*)d_in[1];
    const float* s1    = (const float*)d_in[2];
    const float* s2    = (const float*)d_in[3];
    const float* gamma = (const float*)d_in[4];
    const float* beta  = (const float*)d_in[5];
    const int*   h1    = (const int*)d_in[6];
    const int*   h2    = (const int*)d_in[7];
    float* out = (float*)d_out;

    hipLaunchKernelGGL(mcb9, dim3(2048), dim3(NT), 0, stream,
                       x, y, s1, s2, gamma, beta, h1, h2, out);
}